// Round 1
// baseline (406.313 us; speedup 1.0000x reference)
//
#include <hip/hip_runtime.h>
#include <cstdint>
#include <cstddef>

#define TEMP_F 0.5f
#define EPS_F 1e-6f

constexpr int Bc = 8, Tc = 2048, Dc = 512;

// C[m,n] = act( sum_k A[m,k]*Bw[n,k] + bias[n] )   (both row-major, "NT")
template<bool GELU>
__global__ __launch_bounds__(256)
void gemm_nt(const float* __restrict__ A, const float* __restrict__ Bw,
             const float* __restrict__ bias, float* __restrict__ C,
             int M, int N, int K)
{
    __shared__ float As[16][64];   // [k][m]
    __shared__ float Bs[16][64];   // [k][n]
    const int bm = blockIdx.x * 64;
    const int bn = blockIdx.y * 64;
    const int tid = threadIdx.x;
    const int tx = tid & 15;        // col group 0..15
    const int ty = tid >> 4;        // row group 0..15
    const int srow = tid >> 2;      // 0..63 staging row
    const int skk  = (tid & 3) << 2; // 0,4,8,12 staging k offset

    const float* Aptr = A + (size_t)(bm + srow) * K + skk;
    const float* Bptr = Bw + (size_t)(bn + srow) * K + skk;

    float acc[4][4];
#pragma unroll
    for (int i = 0; i < 4; i++)
#pragma unroll
        for (int j = 0; j < 4; j++) acc[i][j] = 0.0f;

    for (int k0 = 0; k0 < K; k0 += 16) {
        float4 av = *reinterpret_cast<const float4*>(Aptr + k0);
        float4 bv = *reinterpret_cast<const float4*>(Bptr + k0);
        __syncthreads();
        As[skk + 0][srow] = av.x; As[skk + 1][srow] = av.y;
        As[skk + 2][srow] = av.z; As[skk + 3][srow] = av.w;
        Bs[skk + 0][srow] = bv.x; Bs[skk + 1][srow] = bv.y;
        Bs[skk + 2][srow] = bv.z; Bs[skk + 3][srow] = bv.w;
        __syncthreads();
#pragma unroll
        for (int kk = 0; kk < 16; ++kk) {
            float4 a = *reinterpret_cast<const float4*>(&As[kk][ty << 2]);
            float4 b = *reinterpret_cast<const float4*>(&Bs[kk][tx << 2]);
            float ar[4] = {a.x, a.y, a.z, a.w};
            float br[4] = {b.x, b.y, b.z, b.w};
#pragma unroll
            for (int i = 0; i < 4; i++)
#pragma unroll
                for (int j = 0; j < 4; j++)
                    acc[i][j] = fmaf(ar[i], br[j], acc[i][j]);
        }
    }
    // epilogue: vectorized store of each 4-wide row chunk
#pragma unroll
    for (int i = 0; i < 4; i++) {
        const int m = bm + (ty << 2) + i;
        const int n0 = bn + (tx << 2);
        float4 v;
        float vv[4];
#pragma unroll
        for (int j = 0; j < 4; j++) {
            float val = acc[i][j];
            if (GELU) {
                val += bias[n0 + j];
                val = 0.5f * val * (1.0f + erff(val * 0.70710678118654752f));
            }
            vv[j] = val;
        }
        v.x = vv[0]; v.y = vv[1]; v.z = vv[2]; v.w = vv[3];
        *reinterpret_cast<float4*>(&C[(size_t)m * N + n0]) = v;
    }
}

// one wave per row: logits = h . W2 + b2; probs, soft, hard
__global__ __launch_bounds__(256)
void logits_kernel(const float* __restrict__ h, const float* __restrict__ W2,
                   const float* __restrict__ b2, const float* __restrict__ u,
                   float* __restrict__ probs, float* __restrict__ bnd, int nrows)
{
    const int wid = threadIdx.x >> 6;
    const int lane = threadIdx.x & 63;
    const int row = blockIdx.x * 4 + wid;
    if (row >= nrows) return;
    const float* hp = h + (size_t)row * Dc + lane * 8;
    const float* wp = W2 + lane * 8;
    float4 h0 = *reinterpret_cast<const float4*>(hp);
    float4 h1 = *reinterpret_cast<const float4*>(hp + 4);
    float4 w0 = *reinterpret_cast<const float4*>(wp);
    float4 w1 = *reinterpret_cast<const float4*>(wp + 4);
    float dot = h0.x * w0.x + h0.y * w0.y + h0.z * w0.z + h0.w * w0.w
              + h1.x * w1.x + h1.y * w1.y + h1.z * w1.z + h1.w * w1.w;
#pragma unroll
    for (int off = 32; off >= 1; off >>= 1) dot += __shfl_xor(dot, off);
    if (lane == 0) {
        float logits = dot + b2[0];
        float p = 1.0f / (1.0f + expf(-logits));
        probs[row] = p;
        float pc = fminf(fmaxf(p, EPS_F), 1.0f - EPS_F);
        float uu = fminf(fmaxf(u[row], EPS_F), 1.0f - EPS_F);
        float z = (logf(pc) - log1pf(-pc) + logf(uu) - log1pf(-uu)) / TEMP_F;
        float soft = 1.0f / (1.0f + expf(-z));
        bnd[row] = (soft > 0.5f) ? 1.0f : 0.0f;
    }
}

// one wave per batch row: boundary fix, exclusive cumsum -> seg ids, counts
__global__ __launch_bounds__(64)
void scan_fix_kernel(float* __restrict__ bnd, int* __restrict__ seg,
                     float* __restrict__ counts, int T)
{
    __shared__ float cnt[Tc];
    const int b = blockIdx.x;
    const int lane = threadIdx.x;
    const int CH = Tc / 64; // 32 elements per lane
    float* rb = bnd + (size_t)b * T;
    float v[CH];
    int lsum = 0;
#pragma unroll
    for (int j = 0; j < CH; j++) {
        v[j] = rb[lane * CH + j];
        lsum += (int)v[j];
    }
    // row total (for the "at least one boundary" fix)
    int tot = lsum;
#pragma unroll
    for (int off = 32; off >= 1; off >>= 1) tot += __shfl_xor(tot, off);
    if (tot == 0 && lane == 63) { v[CH - 1] = 1.0f; rb[T - 1] = 1.0f; }
    // exclusive scan of per-lane sums
    int incl = lsum;
#pragma unroll
    for (int off = 1; off < 64; off <<= 1) {
        int nv = __shfl_up(incl, off);
        if (lane >= off) incl += nv;
    }
    int run = incl - lsum; // boundaries strictly before this lane's chunk
    for (int s = lane; s < T; s += 64) cnt[s] = 0.0f;
    __syncthreads();
#pragma unroll
    for (int j = 0; j < CH; j++) {
        const int sg = run;                 // #boundaries strictly before t
        run += (int)v[j];
        seg[(size_t)b * T + lane * CH + j] = sg;
        atomicAdd(&cnt[sg], 1.0f);
    }
    __syncthreads();
    for (int s = lane; s < T; s += 64) counts[(size_t)b * T + s] = cnt[s];
}

// scatter-add hidden rows into pooled segments
__global__ __launch_bounds__(128)
void scatter_kernel(const float* __restrict__ hidden, const int* __restrict__ seg,
                    float* __restrict__ pooled)
{
    const int row = blockIdx.x;     // b*T + t
    const int b = row >> 11;        // /2048
    const int s = seg[row];
    const float* hp = hidden + (size_t)row * Dc;
    float* pp = pooled + ((size_t)(b << 11) + s) * Dc;
#pragma unroll
    for (int d = threadIdx.x; d < Dc; d += 128)
        atomicAdd(pp + d, hp[d]);
}

// pooled /= clip(counts, 1e-8)
__global__ __launch_bounds__(256)
void divide_kernel(float* __restrict__ pooled, const float* __restrict__ counts, int total4)
{
    const int i = blockIdx.x * 256 + threadIdx.x;
    if (i >= total4) return;
    float4* p = reinterpret_cast<float4*>(pooled) + i;
    const float c = fmaxf(counts[(i * 4) / Dc], 1e-8f);
    const float inv = 1.0f / c;
    float4 v = *p;
    v.x *= inv; v.y *= inv; v.z *= inv; v.w *= inv;
    *p = v;
}

extern "C" void kernel_launch(void* const* d_in, const int* in_sizes, int n_in,
                              void* d_out, int out_size, void* d_ws, size_t ws_size,
                              hipStream_t stream)
{
    const float* x   = (const float*)d_in[0];
    const float* u   = (const float*)d_in[1];
    const float* Wup = (const float*)d_in[2];
    const float* W1  = (const float*)d_in[3];
    const float* b1  = (const float*)d_in[4];
    const float* W2  = (const float*)d_in[5];
    const float* b2  = (const float*)d_in[6];

    float* out = (float*)d_out;
    const size_t pooledN = (size_t)Bc * Tc * Dc;   // 8388608
    float* pooled = out;
    float* bnd    = out + pooledN;
    float* probs  = bnd + (size_t)Bc * Tc;
    float* hidden = probs + (size_t)Bc * Tc;

    int*   seg    = (int*)d_ws;
    float* counts = (float*)((char*)d_ws + sizeof(int) * Bc * Tc);
    float* hbuf   = pooled;   // reuse pooled region to hold h until memset

    const int M = Bc * Tc;    // 16384
    dim3 gemmGrid(M / 64, Dc / 64);

    // 1) hidden = x @ W_up^T
    gemm_nt<false><<<gemmGrid, 256, 0, stream>>>(x, Wup, nullptr, hidden, M, Dc, Dc);
    // 2) h = gelu(hidden @ W1^T + b1)   (stored in pooled region)
    gemm_nt<true ><<<gemmGrid, 256, 0, stream>>>(hidden, W1, b1, hbuf, M, Dc, Dc);
    // 3) logits -> probs, hard boundaries
    logits_kernel<<<M / 4, 256, 0, stream>>>(hbuf, W2, b2, u, probs, bnd, M);
    // 4) boundary fix + seg ids + counts
    scan_fix_kernel<<<Bc, 64, 0, stream>>>(bnd, seg, counts, Tc);
    // 5) zero pooled, scatter-add, divide
    hipMemsetAsync(pooled, 0, pooledN * sizeof(float), stream);
    scatter_kernel<<<M, 128, 0, stream>>>(hidden, seg, pooled);
    divide_kernel<<<(int)((pooledN / 4 + 255) / 256), 256, 0, stream>>>(pooled, counts, (int)(pooledN / 4));
}

// Round 2
// 212.548 us; speedup vs baseline: 1.9116x; 1.9116x over previous
//
#include <hip/hip_runtime.h>
#include <cstdint>
#include <cstddef>

typedef _Float16 half8 __attribute__((ext_vector_type(8)));
typedef float floatx4 __attribute__((ext_vector_type(4)));

constexpr int Bc = 8, Tc = 2048, Dc = 512;
constexpr float kSplitScale = 2048.0f;        // 2^11
constexpr float kInvSplit   = 4.8828125e-4f;  // 2^-11 (exact)
constexpr float kF16MinNorm = 6.103515625e-5f;

// Split fp32 -> fp16 hi + (scaled) fp16 lo.  hi is normal-or-zero so MFMA
// denormal-flush (if any) cannot lose it; lo carries (v-hi)*2^11 (normal range).
__global__ __launch_bounds__(256)
void split_kernel(const float* __restrict__ in, _Float16* __restrict__ hi,
                  _Float16* __restrict__ lo, int n8)
{
    int i = blockIdx.x * 256 + threadIdx.x;
    if (i >= n8) return;
    const float4* ip = reinterpret_cast<const float4*>(in) + 2 * i;
    float4 a = ip[0], b = ip[1];
    float v[8] = {a.x, a.y, a.z, a.w, b.x, b.y, b.z, b.w};
    half8 h, l;
#pragma unroll
    for (int e = 0; e < 8; ++e) {
        float hv = (fabsf(v[e]) >= kF16MinNorm) ? (float)(_Float16)v[e] : 0.0f;
        h[e] = (_Float16)hv;
        l[e] = (_Float16)((v[e] - hv) * kSplitScale);
    }
    reinterpret_cast<half8*>(hi)[i] = h;
    reinterpret_cast<half8*>(lo)[i] = l;
}

// C = A @ B^T via fp16-split MFMA.  A: [M][K] (Ah/Al), B: [N][K] (Bh/Bl).
// Combo order: (Ah,Bl), (Al,Bh)  [both scaled 2^11], acc *= 2^-11, then (Ah,Bh).
// LOGITS=false: write C (fp32).  LOGITS=true: bias+exact-GELU, dot with w2,
// atomicAdd per-row partials into logits (C never written).
template<bool LOGITS>
__global__ __launch_bounds__(256)
void mfma_gemm(const _Float16* __restrict__ Ah, const _Float16* __restrict__ Al,
               const _Float16* __restrict__ Bh, const _Float16* __restrict__ Bl,
               float* __restrict__ C, const float* __restrict__ bias,
               const float* __restrict__ w2, float* __restrict__ logits,
               int M, int N, int K)
{
    __shared__ _Float16 As[128 * 64];
    __shared__ _Float16 Bs[128 * 64];
    const int t = threadIdx.x;
    const int bm = blockIdx.x * 128;
    const int bn = blockIdx.y * 128;
    const int lane = t & 63;
    const int wid = t >> 6;
    const int wr = (wid >> 1) * 64;   // wave row offset (0,64)
    const int wc = (wid & 1) * 64;    // wave col offset (0,64)
    const int tr = t >> 3;            // staging row 0..31 (per i-step +32)
    const int tc = t & 7;             // staging 16B slot 0..7
    const int swz = (tc ^ (tr & 7)) * 8;  // swizzled half-offset within 128B row

    floatx4 acc[4][4];
#pragma unroll
    for (int i = 0; i < 4; ++i)
#pragma unroll
        for (int j = 0; j < 4; ++j) acc[i][j] = floatx4{0.f, 0.f, 0.f, 0.f};

    half8 ra[4], rb[4];
    // prefetch combo 0 (Ah, Bl), k0 = 0
#pragma unroll
    for (int i = 0; i < 4; ++i) {
        ra[i] = *reinterpret_cast<const half8*>(Ah + (size_t)(bm + i * 32 + tr) * K + tc * 8);
        rb[i] = *reinterpret_cast<const half8*>(Bl + (size_t)(bn + i * 32 + tr) * K + tc * 8);
    }

    for (int c = 0; c < 3; ++c) {
        for (int k0 = 0; k0 < K; k0 += 64) {
            __syncthreads();              // previous tile's reads complete
#pragma unroll
            for (int i = 0; i < 4; ++i) {
                *reinterpret_cast<half8*>(&As[(i * 32 + tr) * 64 + swz]) = ra[i];
                *reinterpret_cast<half8*>(&Bs[(i * 32 + tr) * 64 + swz]) = rb[i];
            }
            // prefetch next K-step (overlaps with MFMA below)
            int c2 = c, k2 = k0 + 64;
            if (k2 == K) { c2 = c + 1; k2 = 0; }
            if (c2 < 3) {
                const _Float16* an = (c2 == 1) ? Al : Ah;
                const _Float16* bb = (c2 == 0) ? Bl : Bh;
#pragma unroll
                for (int i = 0; i < 4; ++i) {
                    ra[i] = *reinterpret_cast<const half8*>(an + (size_t)(bm + i * 32 + tr) * K + k2 + tc * 8);
                    rb[i] = *reinterpret_cast<const half8*>(bb + (size_t)(bn + i * 32 + tr) * K + k2 + tc * 8);
                }
            }
            __syncthreads();              // staged tile visible
#pragma unroll
            for (int kk = 0; kk < 2; ++kk) {
                half8 af[4], bf[4];
                const int kb = kk * 64 + ((lane >> 4) * 16);  // logical byte-in-row
#pragma unroll
                for (int i = 0; i < 4; ++i) {
                    const int rowa = wr + i * 16 + (lane & 15);
                    af[i] = *reinterpret_cast<const half8*>(
                        reinterpret_cast<const char*>(As) + rowa * 128 + (kb ^ ((rowa & 7) * 16)));
                    const int rowb = wc + i * 16 + (lane & 15);
                    bf[i] = *reinterpret_cast<const half8*>(
                        reinterpret_cast<const char*>(Bs) + rowb * 128 + (kb ^ ((rowb & 7) * 16)));
                }
#pragma unroll
                for (int i = 0; i < 4; ++i)
#pragma unroll
                    for (int j = 0; j < 4; ++j)
                        acc[i][j] = __builtin_amdgcn_mfma_f32_16x16x32_f16(af[i], bf[j], acc[i][j], 0, 0, 0);
            }
        }
        if (c == 1) {   // lo-combos done: undo the 2^11 operand scaling (exact)
#pragma unroll
            for (int i = 0; i < 4; ++i)
#pragma unroll
                for (int j = 0; j < 4; ++j)
#pragma unroll
                    for (int r = 0; r < 4; ++r) acc[i][j][r] *= kInvSplit;
        }
    }

    if (!LOGITS) {
#pragma unroll
        for (int i = 0; i < 4; ++i) {
            const int m = bm + wr + i * 16 + ((lane >> 4) * 4);
#pragma unroll
            for (int j = 0; j < 4; ++j) {
                const int n = bn + wc + j * 16 + (lane & 15);
#pragma unroll
                for (int r = 0; r < 4; ++r)
                    C[(size_t)(m + r) * N + n] = acc[i][j][r];
            }
        }
    } else {
        float b1v[4], w2v[4];
#pragma unroll
        for (int j = 0; j < 4; ++j) {
            const int n = bn + wc + j * 16 + (lane & 15);
            b1v[j] = bias[n];
            w2v[j] = w2[n];
        }
#pragma unroll
        for (int i = 0; i < 4; ++i) {
            float part[4] = {0.f, 0.f, 0.f, 0.f};
#pragma unroll
            for (int j = 0; j < 4; ++j)
#pragma unroll
                for (int r = 0; r < 4; ++r) {
                    const float v = acc[i][j][r] + b1v[j];
                    const float g = 0.5f * v * (1.0f + erff(v * 0.70710678118654752f));
                    part[r] += g * w2v[j];
                }
#pragma unroll
            for (int r = 0; r < 4; ++r) {
                float p = part[r];
                p += __shfl_xor(p, 1);
                p += __shfl_xor(p, 2);
                p += __shfl_xor(p, 4);
                p += __shfl_xor(p, 8);
                if ((lane & 15) == 0) {
                    const int m = bm + wr + i * 16 + ((lane >> 4) * 4) + r;
                    atomicAdd(&logits[m], p);
                }
            }
        }
    }
}

__global__ __launch_bounds__(256)
void probs_bnd_kernel(const float* __restrict__ logits, const float* __restrict__ b2,
                      const float* __restrict__ u, float* __restrict__ probs,
                      float* __restrict__ bnd, int n)
{
    int i = blockIdx.x * 256 + threadIdx.x;
    if (i >= n) return;
    const float lg = logits[i] + b2[0];
    const float p = 1.0f / (1.0f + expf(-lg));
    probs[i] = p;
    const float pc = fminf(fmaxf(p, 1e-6f), 1.0f - 1e-6f);
    const float uu = fminf(fmaxf(u[i], 1e-6f), 1.0f - 1e-6f);
    const float z = (logf(pc) - log1pf(-pc) + logf(uu) - log1pf(-uu)) * 2.0f;  // /TEMP=0.5
    bnd[i] = (z > 0.0f) ? 1.0f : 0.0f;   // sigmoid(z) > 0.5  <=>  z > 0
}

// per batch row: at-least-one-boundary fix, segment starts + counts
__global__ __launch_bounds__(64)
void scan_fix(float* __restrict__ bnd, int* __restrict__ starts, float* __restrict__ counts)
{
    __shared__ float cnt[Tc];
    const int b = blockIdx.x;
    const int lane = threadIdx.x;
    constexpr int CH = Tc / 64;  // 32
    float* rb = bnd + (size_t)b * Tc;
    float v[CH];
    int lsum = 0;
#pragma unroll
    for (int j = 0; j < CH; ++j) { v[j] = rb[lane * CH + j]; lsum += (v[j] > 0.5f); }
    int tot = lsum;
#pragma unroll
    for (int off = 32; off >= 1; off >>= 1) tot += __shfl_xor(tot, off);
    const float prevLast = __shfl_up(v[CH - 1], 1);
    if (tot == 0 && lane == 63) { v[CH - 1] = 1.0f; rb[Tc - 1] = 1.0f; }
    int incl = lsum;
#pragma unroll
    for (int off = 1; off < 64; off <<= 1) {
        const int nv = __shfl_up(incl, off);
        if (lane >= off) incl += nv;
    }
    int run = incl - lsum;               // boundaries strictly before this chunk
    for (int s = lane; s < Tc; s += 64) cnt[s] = 0.0f;
    __syncthreads();
    float prev = (lane == 0) ? 1.0f : prevLast;  // t==0 is a segment start
#pragma unroll
    for (int j = 0; j < CH; ++j) {
        const int t_ = lane * CH + j;
        if (prev > 0.5f) starts[(size_t)b * Tc + run] = t_;
        atomicAdd(&cnt[run], 1.0f);
        run += (v[j] > 0.5f);
        prev = v[j];
    }
    __syncthreads();
    for (int s = lane; s < Tc; s += 64) counts[(size_t)b * Tc + s] = cnt[s];
}

// one block per (b, s): mean over the segment's contiguous token range
__global__ __launch_bounds__(128)
void pool_kernel(const float* __restrict__ hidden, const int* __restrict__ starts,
                 const float* __restrict__ counts, float* __restrict__ pooled)
{
    const int blk = blockIdx.x;          // b*Tc + s
    const int b = blk >> 11;
    float4* outp = reinterpret_cast<float4*>(pooled + (size_t)blk * Dc) + threadIdx.x;
    const float c = counts[blk];
    if (c < 0.5f) { *outp = float4{0.f, 0.f, 0.f, 0.f}; return; }
    const int len = (int)c;
    const int start = starts[blk];
    const float4* hp = reinterpret_cast<const float4*>(
                           hidden + ((size_t)(b << 11) + start) * Dc) + threadIdx.x;
    double s0 = 0, s1 = 0, s2 = 0, s3 = 0;
    for (int r = 0; r < len; ++r) {
        const float4 v = hp[(size_t)r * (Dc / 4)];
        s0 += v.x; s1 += v.y; s2 += v.z; s3 += v.w;
    }
    const double inv = 1.0 / (double)len;
    *outp = float4{(float)(s0 * inv), (float)(s1 * inv), (float)(s2 * inv), (float)(s3 * inv)};
}

extern "C" void kernel_launch(void* const* d_in, const int* in_sizes, int n_in,
                              void* d_out, int out_size, void* d_ws, size_t ws_size,
                              hipStream_t stream)
{
    const float* x   = (const float*)d_in[0];
    const float* u   = (const float*)d_in[1];
    const float* Wup = (const float*)d_in[2];
    const float* W1  = (const float*)d_in[3];
    const float* b1  = (const float*)d_in[4];
    const float* W2  = (const float*)d_in[5];
    const float* b2  = (const float*)d_in[6];

    float* out = (float*)d_out;
    const size_t MT = (size_t)Bc * Tc;        // 16384
    const size_t pooledN = MT * Dc;           // 8,388,608
    float* pooled = out;
    float* bnd    = out + pooledN;
    float* probs  = bnd + MT;
    float* hidden = probs + MT;

    // fp16-split scratch lives in the pooled output region (written last):
    // xh/xl during GEMM1, then reused as hh/hl for GEMM2.
    _Float16* xh = (_Float16*)pooled;
    _Float16* xl = xh + pooledN;
    _Float16* hh = xh;
    _Float16* hl = xl;

    char* ws = (char*)d_ws;
    _Float16* wuh = (_Float16*)ws;  ws += (size_t)Dc * Dc * 2;
    _Float16* wul = (_Float16*)ws;  ws += (size_t)Dc * Dc * 2;
    _Float16* w1h = (_Float16*)ws;  ws += (size_t)Dc * Dc * 2;
    _Float16* w1l = (_Float16*)ws;  ws += (size_t)Dc * Dc * 2;
    float* logits = (float*)ws;     ws += MT * 4;
    int*   starts = (int*)ws;       ws += MT * 4;
    float* counts = (float*)ws;     ws += MT * 4;

    const int M = (int)MT, N = Dc, K = Dc;

    split_kernel<<<(M * K / 8 + 255) / 256, 256, 0, stream>>>(x, xh, xl, M * K / 8);
    split_kernel<<<(K * K / 8 + 255) / 256, 256, 0, stream>>>(Wup, wuh, wul, K * K / 8);
    split_kernel<<<(K * K / 8 + 255) / 256, 256, 0, stream>>>(W1, w1h, w1l, K * K / 8);

    dim3 gg(M / 128, N / 128);
    mfma_gemm<false><<<gg, 256, 0, stream>>>(xh, xl, wuh, wul, hidden,
                                             nullptr, nullptr, nullptr, M, N, K);
    split_kernel<<<(M * K / 8 + 255) / 256, 256, 0, stream>>>(hidden, hh, hl, M * K / 8);
    hipMemsetAsync(logits, 0, MT * 4, stream);
    mfma_gemm<true><<<gg, 256, 0, stream>>>(hh, hl, w1h, w1l, nullptr,
                                            b1, W2, logits, M, N, K);
    probs_bnd_kernel<<<((int)MT + 255) / 256, 256, 0, stream>>>(logits, b2, u, probs, bnd, (int)MT);
    scan_fix<<<Bc, 64, 0, stream>>>(bnd, starts, counts);
    pool_kernel<<<(int)MT, 128, 0, stream>>>(hidden, starts, counts, pooled);
}

// Round 4
// 204.451 us; speedup vs baseline: 1.9873x; 1.0396x over previous
//
#include <hip/hip_runtime.h>
#include <cstdint>
#include <cstddef>

typedef _Float16 half8 __attribute__((ext_vector_type(8)));
typedef float floatx4 __attribute__((ext_vector_type(4)));

constexpr int Bc = 8, Tc = 2048, Dc = 512;
constexpr float kSplitScale = 2048.0f;        // 2^11
constexpr float kInvSplit   = 4.8828125e-4f;  // 2^-11 (exact)
constexpr float kF16MinNorm = 6.103515625e-5f;

__device__ __forceinline__ void split8(const float* __restrict__ in, _Float16* __restrict__ hi,
                                       _Float16* __restrict__ lo, int i)
{
    const float4* ip = reinterpret_cast<const float4*>(in) + 2 * i;
    float4 a = ip[0], b = ip[1];
    float v[8] = {a.x, a.y, a.z, a.w, b.x, b.y, b.z, b.w};
    half8 h, l;
#pragma unroll
    for (int e = 0; e < 8; ++e) {
        float hv = (fabsf(v[e]) >= kF16MinNorm) ? (float)(_Float16)v[e] : 0.0f;
        h[e] = (_Float16)hv;
        l[e] = (_Float16)((v[e] - hv) * kSplitScale);
    }
    reinterpret_cast<half8*>(hi)[i] = h;
    reinterpret_cast<half8*>(lo)[i] = l;
}

// single-tensor split (for hidden)
__global__ __launch_bounds__(256)
void split_kernel(const float* __restrict__ in, _Float16* __restrict__ hi,
                  _Float16* __restrict__ lo, int n8)
{
    int i = blockIdx.x * 256 + threadIdx.x;
    if (i >= n8) return;
    split8(in, hi, lo, i);
}

// fused split of x, W_up, W1 in one launch
__global__ __launch_bounds__(256)
void split3_kernel(const float* __restrict__ x,  _Float16* __restrict__ xh,  _Float16* __restrict__ xl,  int nx8,
                   const float* __restrict__ wu, _Float16* __restrict__ wuh, _Float16* __restrict__ wul, int nw8,
                   const float* __restrict__ w1, _Float16* __restrict__ w1h, _Float16* __restrict__ w1l)
{
    int i = blockIdx.x * 256 + threadIdx.x;
    if (i < nx8) { split8(x, xh, xl, i); return; }
    i -= nx8;
    if (i < nw8) { split8(wu, wuh, wul, i); return; }
    i -= nw8;
    if (i < nw8) { split8(w1, w1h, w1l, i); return; }
}

// C = A @ B^T via fp16-split MFMA.  A: [M][K] (Ah/Al), B: [N][K] (Bh/Bl).
// Combo order: (Ah,Bl), (Al,Bh) [operands pre-scaled 2^11], acc *= 2^-11,
// then (Ah,Bh).  Staging: global_load_lds with linear LDS dest + inverse-
// swizzled per-lane global source; reads apply the same XOR involution.
template<bool LOGITS>
__global__ __launch_bounds__(256)
void mfma_gemm(const _Float16* __restrict__ Ah, const _Float16* __restrict__ Al,
               const _Float16* __restrict__ Bh, const _Float16* __restrict__ Bl,
               float* __restrict__ C, const float* __restrict__ bias,
               const float* __restrict__ w2, float* __restrict__ logits,
               int M, int N, int K)
{
    __shared__ _Float16 As[128 * 64];
    __shared__ _Float16 Bs[128 * 64];
    const int t = threadIdx.x;
    const int bm = blockIdx.x * 128;
    const int bn = blockIdx.y * 128;
    const int lane = t & 63;
    const int wid = t >> 6;
    const int wr = (wid >> 1) * 64;   // wave row offset (0,64)
    const int wc = (wid & 1) * 64;    // wave col offset (0,64)
    const int rr = lane >> 3;         // row within 8-row group, == row&7
    const int ss = lane & 7;          // 16B slot 0..7
    const int gchunk = (ss ^ rr) * 8; // inverse-swizzled source chunk (elements)

    floatx4 acc[4][4];
#pragma unroll
    for (int i = 0; i < 4; ++i)
#pragma unroll
        for (int j = 0; j < 4; ++j) acc[i][j] = floatx4{0.f, 0.f, 0.f, 0.f};

    for (int c = 0; c < 3; ++c) {
        const _Float16* Asrc = (c == 1) ? Al : Ah;
        const _Float16* Bsrc = (c == 0) ? Bl : Bh;
        for (int k0 = 0; k0 < K; k0 += 64) {
            __syncthreads();          // previous tile's reads complete
#pragma unroll
            for (int i = 0; i < 4; ++i) {
                const int rbase = i * 32 + wid * 8;   // wave-uniform, mult of 8
                __builtin_amdgcn_global_load_lds(
                    (const __attribute__((address_space(1))) void*)
                        (Asrc + (size_t)(bm + rbase + rr) * K + k0 + gchunk),
                    (__attribute__((address_space(3))) void*)(As + rbase * 64),
                    16, 0, 0);
                __builtin_amdgcn_global_load_lds(
                    (const __attribute__((address_space(1))) void*)
                        (Bsrc + (size_t)(bn + rbase + rr) * K + k0 + gchunk),
                    (__attribute__((address_space(3))) void*)(Bs + rbase * 64),
                    16, 0, 0);
            }
            __syncthreads();          // staged tile visible (compiler drains vmcnt)
#pragma unroll
            for (int kk = 0; kk < 2; ++kk) {
                half8 af[4], bf[4];
                const int kb = kk * 64 + ((lane >> 4) * 16);  // logical byte-in-row
#pragma unroll
                for (int i = 0; i < 4; ++i) {
                    const int rowa = wr + i * 16 + (lane & 15);
                    af[i] = *reinterpret_cast<const half8*>(
                        reinterpret_cast<const char*>(As) + rowa * 128 + (kb ^ ((rowa & 7) * 16)));
                    const int rowb = wc + i * 16 + (lane & 15);
                    bf[i] = *reinterpret_cast<const half8*>(
                        reinterpret_cast<const char*>(Bs) + rowb * 128 + (kb ^ ((rowb & 7) * 16)));
                }
#pragma unroll
                for (int i = 0; i < 4; ++i)
#pragma unroll
                    for (int j = 0; j < 4; ++j)
                        acc[i][j] = __builtin_amdgcn_mfma_f32_16x16x32_f16(af[i], bf[j], acc[i][j], 0, 0, 0);
            }
        }
        if (c == 1) {   // lo-combos done: undo the 2^11 operand scaling (exact)
#pragma unroll
            for (int i = 0; i < 4; ++i)
#pragma unroll
                for (int j = 0; j < 4; ++j)
#pragma unroll
                    for (int r = 0; r < 4; ++r) acc[i][j][r] *= kInvSplit;
        }
    }

    if (!LOGITS) {
#pragma unroll
        for (int i = 0; i < 4; ++i) {
            const int m = bm + wr + i * 16 + ((lane >> 4) * 4);
#pragma unroll
            for (int j = 0; j < 4; ++j) {
                const int n = bn + wc + j * 16 + (lane & 15);
#pragma unroll
                for (int r = 0; r < 4; ++r)
                    C[(size_t)(m + r) * N + n] = acc[i][j][r];
            }
        }
    } else {
        float b1v[4], w2v[4];
#pragma unroll
        for (int j = 0; j < 4; ++j) {
            const int n = bn + wc + j * 16 + (lane & 15);
            b1v[j] = bias[n];
            w2v[j] = w2[n];
        }
#pragma unroll
        for (int i = 0; i < 4; ++i) {
            float part[4] = {0.f, 0.f, 0.f, 0.f};
#pragma unroll
            for (int j = 0; j < 4; ++j)
#pragma unroll
                for (int r = 0; r < 4; ++r) {
                    const float v = acc[i][j][r] + b1v[j];
                    const float g = 0.5f * v * (1.0f + erff(v * 0.70710678118654752f));
                    part[r] += g * w2v[j];
                }
#pragma unroll
            for (int r = 0; r < 4; ++r) {
                float p = part[r];
                p += __shfl_xor(p, 1);
                p += __shfl_xor(p, 2);
                p += __shfl_xor(p, 4);
                p += __shfl_xor(p, 8);
                if ((lane & 15) == 0) {
                    const int m = bm + wr + i * 16 + ((lane >> 4) * 4) + r;
                    atomicAdd(&logits[m], p);
                }
            }
        }
    }
}

__global__ __launch_bounds__(256)
void probs_bnd_kernel(const float* __restrict__ logits, const float* __restrict__ b2,
                      const float* __restrict__ u, float* __restrict__ probs,
                      float* __restrict__ bnd, int n)
{
    int i = blockIdx.x * 256 + threadIdx.x;
    if (i >= n) return;
    const float lg = logits[i] + b2[0];
    const float p = 1.0f / (1.0f + expf(-lg));
    probs[i] = p;
    const float pc = fminf(fmaxf(p, 1e-6f), 1.0f - 1e-6f);
    const float uu = fminf(fmaxf(u[i], 1e-6f), 1.0f - 1e-6f);
    const float z = (logf(pc) - log1pf(-pc) + logf(uu) - log1pf(-uu)) * 2.0f;  // /TEMP=0.5
    bnd[i] = (z > 0.0f) ? 1.0f : 0.0f;   // sigmoid(z) > 0.5  <=>  z > 0
}

// per batch row: at-least-one-boundary fix, segment starts + counts
__global__ __launch_bounds__(64)
void scan_fix(float* __restrict__ bnd, int* __restrict__ starts, float* __restrict__ counts)
{
    __shared__ float cnt[Tc];
    const int b = blockIdx.x;
    const int lane = threadIdx.x;
    constexpr int CH = Tc / 64;  // 32
    float* rb = bnd + (size_t)b * Tc;
    float v[CH];
    int lsum = 0;
#pragma unroll
    for (int j = 0; j < CH; ++j) { v[j] = rb[lane * CH + j]; lsum += (v[j] > 0.5f); }
    int tot = lsum;
#pragma unroll
    for (int off = 32; off >= 1; off >>= 1) tot += __shfl_xor(tot, off);
    const float prevLast = __shfl_up(v[CH - 1], 1);
    if (tot == 0 && lane == 63) { v[CH - 1] = 1.0f; rb[Tc - 1] = 1.0f; }
    int incl = lsum;
#pragma unroll
    for (int off = 1; off < 64; off <<= 1) {
        const int nv = __shfl_up(incl, off);
        if (lane >= off) incl += nv;
    }
    int run = incl - lsum;               // boundaries strictly before this chunk
    for (int s = lane; s < Tc; s += 64) cnt[s] = 0.0f;
    __syncthreads();
    float prev = (lane == 0) ? 1.0f : prevLast;  // t==0 is a segment start
#pragma unroll
    for (int j = 0; j < CH; ++j) {
        const int t_ = lane * CH + j;
        if (prev > 0.5f) starts[(size_t)b * Tc + run] = t_;
        atomicAdd(&cnt[run], 1.0f);
        run += (v[j] > 0.5f);
        prev = v[j];
    }
    __syncthreads();
    for (int s = lane; s < Tc; s += 64) counts[(size_t)b * Tc + s] = cnt[s];
}

// one block per (b, s): mean over the segment's contiguous token range
__global__ __launch_bounds__(128)
void pool_kernel(const float* __restrict__ hidden, const int* __restrict__ starts,
                 const float* __restrict__ counts, float* __restrict__ pooled)
{
    const int blk = blockIdx.x;          // b*Tc + s
    const int b = blk >> 11;
    float4* outp = reinterpret_cast<float4*>(pooled + (size_t)blk * Dc) + threadIdx.x;
    const float c = counts[blk];
    if (c < 0.5f) { *outp = float4{0.f, 0.f, 0.f, 0.f}; return; }
    const int len = (int)c;
    const int start = starts[blk];
    const float4* hp = reinterpret_cast<const float4*>(
                           hidden + ((size_t)(b << 11) + start) * Dc) + threadIdx.x;
    double s0 = 0, s1 = 0, s2 = 0, s3 = 0;
    for (int r = 0; r < len; ++r) {
        const float4 v = hp[(size_t)r * (Dc / 4)];
        s0 += v.x; s1 += v.y; s2 += v.z; s3 += v.w;
    }
    const double inv = 1.0 / (double)len;
    *outp = float4{(float)(s0 * inv), (float)(s1 * inv), (float)(s2 * inv), (float)(s3 * inv)};
}

extern "C" void kernel_launch(void* const* d_in, const int* in_sizes, int n_in,
                              void* d_out, int out_size, void* d_ws, size_t ws_size,
                              hipStream_t stream)
{
    const float* x   = (const float*)d_in[0];
    const float* u   = (const float*)d_in[1];
    const float* Wup = (const float*)d_in[2];
    const float* W1  = (const float*)d_in[3];
    const float* b1  = (const float*)d_in[4];
    const float* W2  = (const float*)d_in[5];
    const float* b2  = (const float*)d_in[6];

    float* out = (float*)d_out;
    const size_t MT = (size_t)Bc * Tc;        // 16384
    const size_t pooledN = MT * Dc;           // 8,388,608
    float* pooled = out;
    float* bnd    = out + pooledN;
    float* probs  = bnd + MT;
    float* hidden = probs + MT;

    // fp16-split scratch lives in the pooled output region (written last):
    // xh/xl during GEMM1, then reused as hh/hl for GEMM2.
    _Float16* xh = (_Float16*)pooled;
    _Float16* xl = xh + pooledN;
    _Float16* hh = xh;
    _Float16* hl = xl;

    char* ws = (char*)d_ws;
    _Float16* wuh = (_Float16*)ws;  ws += (size_t)Dc * Dc * 2;
    _Float16* wul = (_Float16*)ws;  ws += (size_t)Dc * Dc * 2;
    _Float16* w1h = (_Float16*)ws;  ws += (size_t)Dc * Dc * 2;
    _Float16* w1l = (_Float16*)ws;  ws += (size_t)Dc * Dc * 2;
    float* logits = (float*)ws;     ws += MT * 4;
    int*   starts = (int*)ws;       ws += MT * 4;
    float* counts = (float*)ws;     ws += MT * 4;

    const int M = (int)MT, N = Dc, K = Dc;
    const int nx8 = M * K / 8;        // 1,048,576
    const int nw8 = K * K / 8;        // 32,768

    split3_kernel<<<(nx8 + 2 * nw8 + 255) / 256, 256, 0, stream>>>(
        x, xh, xl, nx8, Wup, wuh, wul, nw8, W1, w1h, w1l);

    dim3 gg(M / 128, N / 128);
    mfma_gemm<false><<<gg, 256, 0, stream>>>(xh, xl, wuh, wul, hidden,
                                             nullptr, nullptr, nullptr, M, N, K);
    split_kernel<<<(nx8 + 255) / 256, 256, 0, stream>>>(hidden, hh, hl, nx8);
    hipMemsetAsync(logits, 0, MT * 4, stream);
    mfma_gemm<true><<<gg, 256, 0, stream>>>(hh, hl, w1h, w1l, nullptr,
                                            b1, W2, logits, M, N, K);
    probs_bnd_kernel<<<((int)MT + 255) / 256, 256, 0, stream>>>(logits, b2, u, probs, bnd, (int)MT);
    scan_fix<<<Bc, 64, 0, stream>>>(bnd, starts, counts);
    pool_kernel<<<(int)MT, 128, 0, stream>>>(hidden, starts, counts, pooled);
}

// Round 5
// 202.142 us; speedup vs baseline: 2.0100x; 1.0114x over previous
//
#include <hip/hip_runtime.h>
#include <cstdint>
#include <cstddef>

typedef _Float16 half8 __attribute__((ext_vector_type(8)));
typedef float floatx4 __attribute__((ext_vector_type(4)));

constexpr int Bc = 8, Tc = 2048, Dc = 512;
constexpr float kSplitScale = 2048.0f;        // 2^11
constexpr float kInvSplit   = 4.8828125e-4f;  // 2^-11 (exact)
constexpr float kF16MinNorm = 6.103515625e-5f;

__device__ __forceinline__ void split8(const float* __restrict__ in, _Float16* __restrict__ hi,
                                       _Float16* __restrict__ lo, int i)
{
    const float4* ip = reinterpret_cast<const float4*>(in) + 2 * i;
    float4 a = ip[0], b = ip[1];
    float v[8] = {a.x, a.y, a.z, a.w, b.x, b.y, b.z, b.w};
    half8 h, l;
#pragma unroll
    for (int e = 0; e < 8; ++e) {
        float hv = (fabsf(v[e]) >= kF16MinNorm) ? (float)(_Float16)v[e] : 0.0f;
        h[e] = (_Float16)hv;
        l[e] = (_Float16)((v[e] - hv) * kSplitScale);
    }
    reinterpret_cast<half8*>(hi)[i] = h;
    reinterpret_cast<half8*>(lo)[i] = l;
}

// single-tensor split (for hidden)
__global__ __launch_bounds__(256)
void split_kernel(const float* __restrict__ in, _Float16* __restrict__ hi,
                  _Float16* __restrict__ lo, int n8)
{
    int i = blockIdx.x * 256 + threadIdx.x;
    if (i >= n8) return;
    split8(in, hi, lo, i);
}

// fused split of x, W_up, W1 in one launch
__global__ __launch_bounds__(256)
void split3_kernel(const float* __restrict__ x,  _Float16* __restrict__ xh,  _Float16* __restrict__ xl,  int nx8,
                   const float* __restrict__ wu, _Float16* __restrict__ wuh, _Float16* __restrict__ wul, int nw8,
                   const float* __restrict__ w1, _Float16* __restrict__ w1h, _Float16* __restrict__ w1l)
{
    int i = blockIdx.x * 256 + threadIdx.x;
    if (i < nx8) { split8(x, xh, xl, i); return; }
    i -= nx8;
    if (i < nw8) { split8(wu, wuh, wul, i); return; }
    i -= nw8;
    if (i < nw8) { split8(w1, w1h, w1l, i); return; }
}

// C = A @ B^T via fp16-split MFMA.  A: [M][K] (Ah/Al), B: [N][K] (Bh/Bl).
// Flat step t in [0,24): combo c = t>>3 over {(Ah,Bl),(Al,Bh),(Ah,Bh)},
// k0 = (t&7)*64; acc *= 2^-11 after step 15 (lo-combos done; exact pow2).
// 2-phase pipeline: STAGE(t+1 -> buf^1) || compute(buf) ; one barrier/step.
// global_load_lds: linear LDS dest, inverse-swizzled global source; the
// compute-side ds_read applies the same XOR involution.
template<bool LOGITS>
__global__ __launch_bounds__(256)
void mfma_gemm(const _Float16* __restrict__ Ah, const _Float16* __restrict__ Al,
               const _Float16* __restrict__ Bh, const _Float16* __restrict__ Bl,
               float* __restrict__ C, const float* __restrict__ bias,
               const float* __restrict__ w2, float* __restrict__ logits,
               int M, int N, int K)
{
    __shared__ _Float16 As[2][128 * 64];
    __shared__ _Float16 Bs[2][128 * 64];
    const int t = threadIdx.x;
    const int bm = blockIdx.x * 128;
    const int bn = blockIdx.y * 128;
    const int lane = t & 63;
    const int wid = t >> 6;
    const int wr = (wid >> 1) * 64;   // wave row offset (0,64)
    const int wc = (wid & 1) * 64;    // wave col offset (0,64)
    const int rr = lane >> 3;         // row within 8-row group, == row&7
    const int ss = lane & 7;          // 16B slot 0..7
    const int gchunk = (ss ^ rr) * 8; // inverse-swizzled source chunk (elements)

    floatx4 acc[4][4];
#pragma unroll
    for (int i = 0; i < 4; ++i)
#pragma unroll
        for (int j = 0; j < 4; ++j) acc[i][j] = floatx4{0.f, 0.f, 0.f, 0.f};

    auto stage = [&](int st) {
        const int c  = st >> 3;
        const int k0 = (st & 7) << 6;
        const _Float16* Asrc = (c == 1) ? Al : Ah;
        const _Float16* Bsrc = (c == 0) ? Bl : Bh;
        _Float16* Ad = As[st & 1];
        _Float16* Bd = Bs[st & 1];
#pragma unroll
        for (int i = 0; i < 4; ++i) {
            const int rbase = i * 32 + wid * 8;   // wave-uniform, mult of 8
            __builtin_amdgcn_global_load_lds(
                (const __attribute__((address_space(1))) void*)
                    (Asrc + (size_t)(bm + rbase + rr) * K + k0 + gchunk),
                (__attribute__((address_space(3))) void*)(Ad + rbase * 64),
                16, 0, 0);
            __builtin_amdgcn_global_load_lds(
                (const __attribute__((address_space(1))) void*)
                    (Bsrc + (size_t)(bn + rbase + rr) * K + k0 + gchunk),
                (__attribute__((address_space(3))) void*)(Bd + rbase * 64),
                16, 0, 0);
        }
    };

    stage(0);
    __syncthreads();                  // tile 0 staged (implicit vmcnt(0) drain)

#pragma unroll 2
    for (int st = 0; st < 24; ++st) {
        if (st < 23) stage(st + 1);   // in flight across the MFMA phase
        const char* Ab = reinterpret_cast<const char*>(As[st & 1]);
        const char* Bb = reinterpret_cast<const char*>(Bs[st & 1]);
#pragma unroll
        for (int kk = 0; kk < 2; ++kk) {
            half8 af[4], bf[4];
            const int kb = kk * 64 + ((lane >> 4) * 16);  // logical byte-in-row
#pragma unroll
            for (int i = 0; i < 4; ++i) {
                const int rowa = wr + i * 16 + (lane & 15);
                af[i] = *reinterpret_cast<const half8*>(Ab + rowa * 128 + (kb ^ ((rowa & 7) * 16)));
                const int rowb = wc + i * 16 + (lane & 15);
                bf[i] = *reinterpret_cast<const half8*>(Bb + rowb * 128 + (kb ^ ((rowb & 7) * 16)));
            }
#pragma unroll
            for (int i = 0; i < 4; ++i)
#pragma unroll
                for (int j = 0; j < 4; ++j)
                    acc[i][j] = __builtin_amdgcn_mfma_f32_16x16x32_f16(af[i], bf[j], acc[i][j], 0, 0, 0);
        }
        if (st == 15) {   // lo-combos done: undo the 2^11 operand scaling (exact)
#pragma unroll
            for (int i = 0; i < 4; ++i)
#pragma unroll
                for (int j = 0; j < 4; ++j)
#pragma unroll
                    for (int r = 0; r < 4; ++r) acc[i][j][r] *= kInvSplit;
        }
        __syncthreads();  // drains this step's STAGE; tile st+1 ready
    }

    if (!LOGITS) {
#pragma unroll
        for (int i = 0; i < 4; ++i) {
            const int m = bm + wr + i * 16 + ((lane >> 4) * 4);
#pragma unroll
            for (int j = 0; j < 4; ++j) {
                const int n = bn + wc + j * 16 + (lane & 15);
#pragma unroll
                for (int r = 0; r < 4; ++r)
                    C[(size_t)(m + r) * N + n] = acc[i][j][r];
            }
        }
    } else {
        float b1v[4], w2v[4];
#pragma unroll
        for (int j = 0; j < 4; ++j) {
            const int n = bn + wc + j * 16 + (lane & 15);
            b1v[j] = bias[n];
            w2v[j] = w2[n];
        }
#pragma unroll
        for (int i = 0; i < 4; ++i) {
            float part[4] = {0.f, 0.f, 0.f, 0.f};
#pragma unroll
            for (int j = 0; j < 4; ++j)
#pragma unroll
                for (int r = 0; r < 4; ++r) {
                    const float v = acc[i][j][r] + b1v[j];
                    const float g = 0.5f * v * (1.0f + erff(v * 0.70710678118654752f));
                    part[r] += g * w2v[j];
                }
#pragma unroll
            for (int r = 0; r < 4; ++r) {
                float p = part[r];
                p += __shfl_xor(p, 1);
                p += __shfl_xor(p, 2);
                p += __shfl_xor(p, 4);
                p += __shfl_xor(p, 8);
                if ((lane & 15) == 0) {
                    const int m = bm + wr + i * 16 + ((lane >> 4) * 4) + r;
                    atomicAdd(&logits[m], p);
                }
            }
        }
    }
}

__global__ __launch_bounds__(256)
void probs_bnd_kernel(const float* __restrict__ logits, const float* __restrict__ b2,
                      const float* __restrict__ u, float* __restrict__ probs,
                      float* __restrict__ bnd, int n)
{
    int i = blockIdx.x * 256 + threadIdx.x;
    if (i >= n) return;
    const float lg = logits[i] + b2[0];
    const float p = 1.0f / (1.0f + expf(-lg));
    probs[i] = p;
    const float pc = fminf(fmaxf(p, 1e-6f), 1.0f - 1e-6f);
    const float uu = fminf(fmaxf(u[i], 1e-6f), 1.0f - 1e-6f);
    const float z = (logf(pc) - log1pf(-pc) + logf(uu) - log1pf(-uu)) * 2.0f;  // /TEMP=0.5
    bnd[i] = (z > 0.0f) ? 1.0f : 0.0f;   // sigmoid(z) > 0.5  <=>  z > 0
}

// per batch row: at-least-one-boundary fix, segment starts + counts
__global__ __launch_bounds__(64)
void scan_fix(float* __restrict__ bnd, int* __restrict__ starts, float* __restrict__ counts)
{
    __shared__ float cnt[Tc];
    const int b = blockIdx.x;
    const int lane = threadIdx.x;
    constexpr int CH = Tc / 64;  // 32
    float* rb = bnd + (size_t)b * Tc;
    float v[CH];
    int lsum = 0;
#pragma unroll
    for (int j = 0; j < CH; ++j) { v[j] = rb[lane * CH + j]; lsum += (v[j] > 0.5f); }
    int tot = lsum;
#pragma unroll
    for (int off = 32; off >= 1; off >>= 1) tot += __shfl_xor(tot, off);
    const float prevLast = __shfl_up(v[CH - 1], 1);
    if (tot == 0 && lane == 63) { v[CH - 1] = 1.0f; rb[Tc - 1] = 1.0f; }
    int incl = lsum;
#pragma unroll
    for (int off = 1; off < 64; off <<= 1) {
        const int nv = __shfl_up(incl, off);
        if (lane >= off) incl += nv;
    }
    int run = incl - lsum;               // boundaries strictly before this chunk
    for (int s = lane; s < Tc; s += 64) cnt[s] = 0.0f;
    __syncthreads();
    float prev = (lane == 0) ? 1.0f : prevLast;  // t==0 is a segment start
#pragma unroll
    for (int j = 0; j < CH; ++j) {
        const int t_ = lane * CH + j;
        if (prev > 0.5f) starts[(size_t)b * Tc + run] = t_;
        atomicAdd(&cnt[run], 1.0f);
        run += (v[j] > 0.5f);
        prev = v[j];
    }
    __syncthreads();
    for (int s = lane; s < Tc; s += 64) counts[(size_t)b * Tc + s] = cnt[s];
}

// one block per (b, s): mean over the segment's contiguous token range
__global__ __launch_bounds__(128)
void pool_kernel(const float* __restrict__ hidden, const int* __restrict__ starts,
                 const float* __restrict__ counts, float* __restrict__ pooled)
{
    const int blk = blockIdx.x;          // b*Tc + s
    const int b = blk >> 11;
    float4* outp = reinterpret_cast<float4*>(pooled + (size_t)blk * Dc) + threadIdx.x;
    const float c = counts[blk];
    if (c < 0.5f) { *outp = float4{0.f, 0.f, 0.f, 0.f}; return; }
    const int len = (int)c;
    const int start = starts[blk];
    const float4* hp = reinterpret_cast<const float4*>(
                           hidden + ((size_t)(b << 11) + start) * Dc) + threadIdx.x;
    double s0 = 0, s1 = 0, s2 = 0, s3 = 0;
    for (int r = 0; r < len; ++r) {
        const float4 v = hp[(size_t)r * (Dc / 4)];
        s0 += v.x; s1 += v.y; s2 += v.z; s3 += v.w;
    }
    const double inv = 1.0 / (double)len;
    *outp = float4{(float)(s0 * inv), (float)(s1 * inv), (float)(s2 * inv), (float)(s3 * inv)};
}

extern "C" void kernel_launch(void* const* d_in, const int* in_sizes, int n_in,
                              void* d_out, int out_size, void* d_ws, size_t ws_size,
                              hipStream_t stream)
{
    const float* x   = (const float*)d_in[0];
    const float* u   = (const float*)d_in[1];
    const float* Wup = (const float*)d_in[2];
    const float* W1  = (const float*)d_in[3];
    const float* b1  = (const float*)d_in[4];
    const float* W2  = (const float*)d_in[5];
    const float* b2  = (const float*)d_in[6];

    float* out = (float*)d_out;
    const size_t MT = (size_t)Bc * Tc;        // 16384
    const size_t pooledN = MT * Dc;           // 8,388,608
    float* pooled = out;
    float* bnd    = out + pooledN;
    float* probs  = bnd + MT;
    float* hidden = probs + MT;

    // fp16-split scratch lives in the pooled output region (written last):
    // xh/xl during GEMM1, then reused as hh/hl for GEMM2.
    _Float16* xh = (_Float16*)pooled;
    _Float16* xl = xh + pooledN;
    _Float16* hh = xh;
    _Float16* hl = xl;

    char* ws = (char*)d_ws;
    _Float16* wuh = (_Float16*)ws;  ws += (size_t)Dc * Dc * 2;
    _Float16* wul = (_Float16*)ws;  ws += (size_t)Dc * Dc * 2;
    _Float16* w1h = (_Float16*)ws;  ws += (size_t)Dc * Dc * 2;
    _Float16* w1l = (_Float16*)ws;  ws += (size_t)Dc * Dc * 2;
    float* logits = (float*)ws;     ws += MT * 4;
    int*   starts = (int*)ws;       ws += MT * 4;
    float* counts = (float*)ws;     ws += MT * 4;

    const int M = (int)MT, N = Dc, K = Dc;
    const int nx8 = M * K / 8;        // 1,048,576
    const int nw8 = K * K / 8;        // 32,768

    split3_kernel<<<(nx8 + 2 * nw8 + 255) / 256, 256, 0, stream>>>(
        x, xh, xl, nx8, Wup, wuh, wul, nw8, W1, w1h, w1l);

    dim3 gg(M / 128, N / 128);
    mfma_gemm<false><<<gg, 256, 0, stream>>>(xh, xl, wuh, wul, hidden,
                                             nullptr, nullptr, nullptr, M, N, K);
    split_kernel<<<(nx8 + 255) / 256, 256, 0, stream>>>(hidden, hh, hl, nx8);
    hipMemsetAsync(logits, 0, MT * 4, stream);
    mfma_gemm<true><<<gg, 256, 0, stream>>>(hh, hl, w1h, w1l, nullptr,
                                            b1, W2, logits, M, N, K);
    probs_bnd_kernel<<<((int)MT + 255) / 256, 256, 0, stream>>>(logits, b2, u, probs, bnd, (int)MT);
    scan_fix<<<Bc, 64, 0, stream>>>(bnd, starts, counts);
    pool_kernel<<<(int)MT, 128, 0, stream>>>(hidden, starts, counts, pooled);
}